// Round 7
// baseline (16.224 us; speedup 1.0000x reference)
//
#include <hip/hip_runtime.h>
#include <hip/hip_bf16.h>
#include <math.h>

#define B_IMG 16
#define H_DIM 640
#define W_DIM 640
#define W4    160                       // float4 per row
#define RPB   8                         // rows per block
#define BLK_F4 (RPB * W4)               // 1280 float4 per block
#define BPI   (H_DIM / RPB)             // 80 blocks per image
#define GRID  (B_IMG * BPI)             // 1280 blocks, each owns 8 rows of ONE image
#define NT    256
#define KITER (BLK_F4 / NT)             // 5 float4 per thread
#define SLOTS (GRID / NT)               // 5 flag/partial slots per finisher thread
#define NWORDS (W_DIM / 32)             // 20 u32 per row bitmask
#define NPIX  ((float)B_IMG * H_DIM * W_DIM)
#define LOSS_WEIGHT 0.1f
#define LN2F 0.69314718055994530942f
#define MAXB 512
#define FIN  (GRID - 1)                 // statically designated finisher block

__device__ __forceinline__ float softplus_fast(float v) {
    return fmaxf(v, 0.0f) + __logf(1.0f + __expf(-fabsf(v)));
}

// ---------------------------------------------------------------------------
// Single fused kernel. Each block owns an 8-row slab of one image:
// prefetch slab -> rasterize own image's boxes -> per-row LDS bitmask ->
// masked softplus reduce -> publish partial via agent-scope atomics (distinct
// addresses: NO contention) + per-block flag. Block FIN then spins on the
// flags, reduces all partials in fixed order, writes the scalar, and resets
// the flags to 0 so the next replay needs no memset node.
// ---------------------------------------------------------------------------
__global__ void __launch_bounds__(NT)
fused_slab(const float4* __restrict__ seg4,
           const float*  __restrict__ bboxes,
           const int*    __restrict__ batch_idx,
           const unsigned char* __restrict__ is_seg,
           int M,
           float*    __restrict__ p1,      // [GRID]
           float*    __restrict__ p2,      // [GRID]
           unsigned* __restrict__ flags,   // [GRID], self-resetting (0 between calls)
           float*    __restrict__ out)
{
    __shared__ int      s_n;
    __shared__ int4     s_box[MAXB];
    __shared__ unsigned s_mask[RPB * NWORDS];
    __shared__ float    s_r1[NT / 64], s_r2[NT / 64];
    __shared__ int      s_has[B_IMG];

    const int tid = threadIdx.x;
    const int bid = blockIdx.x;
    const int b   = bid / BPI;
    const int y0  = (bid - b * BPI) * RPB;

    // --- T14 prefetch: issue all 5 slab loads before LDS/setup work ---
    const size_t base = (size_t)bid * BLK_F4;
    float4 v0 = seg4[base + 0 * NT + tid];
    float4 v1 = seg4[base + 1 * NT + tid];
    float4 v2 = seg4[base + 2 * NT + tid];
    float4 v3 = seg4[base + 3 * NT + tid];
    float4 v4 = seg4[base + 4 * NT + tid];

    if (tid == 0) s_n = 0;
    __syncthreads();

    // --- gather this image's boxes (f32 math, clip [0,dim-1], trunc = ref) ---
    for (int m = tid; m < M; m += NT) {
        int bi = batch_idx[m];
        bi = min(max(bi, 0), B_IMG - 1);
        if (bi == b) {
            float cx = bboxes[4*m+0] * (float)W_DIM;
            float cy = bboxes[4*m+1] * (float)H_DIM;
            float bw = bboxes[4*m+2] * (float)W_DIM;
            float bh = bboxes[4*m+3] * (float)H_DIM;
            int x1 = (int)fminf(fmaxf(cx - bw*0.5f, 0.0f), (float)(W_DIM-1));
            int y1 = (int)fminf(fmaxf(cy - bh*0.5f, 0.0f), (float)(H_DIM-1));
            int x2 = (int)fminf(fmaxf(cx + bw*0.5f, 0.0f), (float)(W_DIM-1));
            int y2 = (int)fminf(fmaxf(cy + bh*0.5f, 0.0f), (float)(H_DIM-1));
            int p = atomicAdd(&s_n, 1);
            if (p < MAXB) s_box[p] = make_int4(x1, y1, x2, y2);
        }
    }
    __syncthreads();
    const int nb  = min(s_n, MAXB);
    const int eff = (is_seg[b] == 0 && nb > 0) ? 1 : 0;

    float sp_sum = 0.0f, mx_sum = 0.0f;

    if (eff) {
        if (tid < RPB * NWORDS) {
            int row  = tid / NWORDS;
            int word = tid - row * NWORDS;
            int y    = y0 + row;
            int wx0  = word * 32;
            unsigned acc = 0u;
            for (int i = 0; i < nb; ++i) {
                int4 bx = s_box[i];
                if (y >= bx.y && y <= bx.w) {
                    int lo = max(bx.x, wx0);
                    int hi = min(bx.z, wx0 + 31);
                    if (lo <= hi) {
                        unsigned span = (unsigned)(hi - lo + 1);
                        unsigned mset = (span >= 32u) ? 0xFFFFFFFFu
                                                      : ((1u << span) - 1u);
                        acc |= mset << (lo - wx0);
                    }
                }
            }
            s_mask[tid] = acc;
        }
        __syncthreads();

        float4 vv[KITER] = {v0, v1, v2, v3, v4};
#pragma unroll
        for (int k = 0; k < KITER; ++k) {
            int idx = k * NT + tid;
            int row = idx / W4;
            int x0  = (idx - row * W4) * 4;
            float4 v = vv[k];
            sp_sum += softplus_fast(v.x) + softplus_fast(v.y)
                    + softplus_fast(v.z) + softplus_fast(v.w);
            unsigned w  = s_mask[row * NWORDS + (x0 >> 5)];
            unsigned mb = (w >> (x0 & 31)) & 0xFu;
            mx_sum += ((mb & 1u) ? v.x : 0.0f) + ((mb & 2u) ? v.y : 0.0f)
                    + ((mb & 4u) ? v.z : 0.0f) + ((mb & 8u) ? v.w : 0.0f);
        }
    }

    // --- deterministic block reduce ---
#pragma unroll
    for (int s = 32; s > 0; s >>= 1) {
        sp_sum += __shfl_xor(sp_sum, s, 64);
        mx_sum += __shfl_xor(mx_sum, s, 64);
    }
    const int wave = tid >> 6;
    if ((tid & 63) == 0) { s_r1[wave] = sp_sum; s_r2[wave] = mx_sum; }
    __syncthreads();
    if (tid == 0) {
        float a1 = 0.0f, a2 = 0.0f;
#pragma unroll
        for (int w = 0; w < NT / 64; ++w) { a1 += s_r1[w]; a2 += s_r2[w]; }
        // Publish through the coherence point (agent-scope RMWs, distinct
        // addresses -> no serialization). vmcnt(0) orders partials < flag.
        __hip_atomic_exchange(&p1[bid], a1, __ATOMIC_RELAXED, __HIP_MEMORY_SCOPE_AGENT);
        __hip_atomic_exchange(&p2[bid], a2, __ATOMIC_RELAXED, __HIP_MEMORY_SCOPE_AGENT);
        asm volatile("s_waitcnt vmcnt(0)" ::: "memory");
        __hip_atomic_exchange(&flags[bid], 1u, __ATOMIC_RELAXED, __HIP_MEMORY_SCOPE_AGENT);
    }
    if (bid != FIN) return;

    // ================= finisher (block FIN only, all 256 threads) ===========
    // Spin until every block's flag is 1. Stale values (0 from the previous
    // replay's reset, or 0xAAAAAAAA from the one-time ws poison) are != 1,
    // so the predicate is correct in every calling context. Only this block
    // waits; producers never wait -> no deadlock under any dispatch order.
#pragma unroll
    for (int k = 0; k < SLOTS; ++k) {
        unsigned f;
        do {
            f = __hip_atomic_fetch_add(&flags[k * NT + tid], 0u,
                                       __ATOMIC_RELAXED, __HIP_MEMORY_SCOPE_AGENT);
        } while (f != 1u);
    }
    __syncthreads();

    // Fixed-order readback via RMW-loads (coherent; +0 exact) -> deterministic.
    float a1 = 0.0f, a2 = 0.0f;
#pragma unroll
    for (int k = 0; k < SLOTS; ++k) {
        a1 += __hip_atomic_fetch_add(&p1[k * NT + tid], 0.0f,
                                     __ATOMIC_RELAXED, __HIP_MEMORY_SCOPE_AGENT);
        a2 += __hip_atomic_fetch_add(&p2[k * NT + tid], 0.0f,
                                     __ATOMIC_RELAXED, __HIP_MEMORY_SCOPE_AGENT);
    }
#pragma unroll
    for (int s = 32; s > 0; s >>= 1) {
        a1 += __shfl_xor(a1, s, 64);
        a2 += __shfl_xor(a2, s, 64);
    }
    __syncthreads();                       // s_r1/s_r2 safely reusable
    if ((tid & 63) == 0) { s_r1[wave] = a1; s_r2[wave] = a2; }
    if (tid < B_IMG) s_has[tid] = 0;
    __syncthreads();
    for (int m = tid; m < M; m += NT) {
        int bi = batch_idx[m];
        bi = min(max(bi, 0), B_IMG - 1);
        s_has[bi] = 1;                     // benign race
    }
    __syncthreads();
    if (tid == 0) {
        float t1 = 0.0f, t2 = 0.0f;
#pragma unroll
        for (int w = 0; w < NT / 64; ++w) { t1 += s_r1[w]; t2 += s_r2[w]; }
        int n_eff = 0;
        for (int bi = 0; bi < B_IMG; ++bi)
            n_eff += (is_seg[bi] == 0 && s_has[bi]) ? 1 : 0;
        float noneff_px = (float)(B_IMG - n_eff) * (float)H_DIM * (float)W_DIM;
        float total = t1 - t2 + LN2F * noneff_px;
        out[0] = (n_eff > 0) ? LOSS_WEIGHT * (total / NPIX) : 0.0f;
    }
    __syncthreads();
    // Self-clean: reset flags to 0 so the next call needs no memset node.
#pragma unroll
    for (int k = 0; k < SLOTS; ++k)
        __hip_atomic_exchange(&flags[k * NT + tid], 0u,
                              __ATOMIC_RELAXED, __HIP_MEMORY_SCOPE_AGENT);
}

// ---------------------------------------------------------------------------
extern "C" void kernel_launch(void* const* d_in, const int* in_sizes, int n_in,
                              void* d_out, int out_size, void* d_ws, size_t ws_size,
                              hipStream_t stream) {
    const float4*        seg4      = (const float4*)d_in[0];
    const float*         bboxes    = (const float*)d_in[1];
    const int*           batch_idx = (const int*)d_in[2];
    const unsigned char* is_seg    = (const unsigned char*)d_in[3];
    float*               out       = (float*)d_out;
    const int M = in_sizes[1] / 4;

    char* ws = (char*)d_ws;
    float*    p1    = (float*)ws;                        // GRID * 4 B
    float*    p2    = (float*)(ws + GRID * 4);           // GRID * 4 B
    unsigned* flags = (unsigned*)(ws + 2 * GRID * 4);    // GRID * 4 B

    fused_slab<<<GRID, NT, 0, stream>>>(seg4, bboxes, batch_idx, is_seg, M,
                                        p1, p2, flags, out);
}